// Round 1
// baseline (16033.563 us; speedup 1.0000x reference)
//
#include <hip/hip_runtime.h>
#include <math.h>

#define B 16
#define S 256
#define VOCAB 30522
#define H 768
#define NH 12
#define DH 64
#define DFF 3072
#define L 12
#define T 9
#define M (B*S)
#define LN_EPS 1e-12f

// ---------------- Embedding + LayerNorm ----------------
__global__ void embed_ln_kernel(const int* __restrict__ x,
                                const float* __restrict__ word_emb,
                                const float* __restrict__ pos_emb,
                                const float* __restrict__ type_emb,
                                const float* __restrict__ g,
                                const float* __restrict__ bta,
                                float* __restrict__ h) {
    int row = blockIdx.x;        // b*S + s
    int s = row % S;
    int tok = x[row];
    int t = threadIdx.x;         // 256 threads, 3 elems each (H=768)
    float vals[3];
    float sum = 0.f;
    for (int i = 0; i < 3; ++i) {
        int c = t + i * 256;
        float val = word_emb[(size_t)tok * H + c] + pos_emb[s * H + c] + type_emb[c];
        vals[i] = val; sum += val;
    }
    __shared__ float red[256];
    red[t] = sum; __syncthreads();
    for (int off = 128; off > 0; off >>= 1) { if (t < off) red[t] += red[t + off]; __syncthreads(); }
    float mean = red[0] * (1.0f / H);
    __syncthreads();
    float vs = 0.f;
    for (int i = 0; i < 3; ++i) { float d = vals[i] - mean; vs += d * d; }
    red[t] = vs; __syncthreads();
    for (int off = 128; off > 0; off >>= 1) { if (t < off) red[t] += red[t + off]; __syncthreads(); }
    float inv = rsqrtf(red[0] * (1.0f / H) + LN_EPS);
    for (int i = 0; i < 3; ++i) {
        int c = t + i * 256;
        h[(size_t)row * H + c] = (vals[i] - mean) * inv * g[c] + bta[c];
    }
}

// ---------------- Residual + LayerNorm (in-place on h) ----------------
__global__ void residual_ln_kernel(float* __restrict__ h,
                                   const float* __restrict__ delta,
                                   const float* __restrict__ g,
                                   const float* __restrict__ bta) {
    int row = blockIdx.x;
    int t = threadIdx.x;
    float vals[3];
    float sum = 0.f;
    for (int i = 0; i < 3; ++i) {
        int c = t + i * 256;
        float val = h[(size_t)row * H + c] + delta[(size_t)row * H + c];
        vals[i] = val; sum += val;
    }
    __shared__ float red[256];
    red[t] = sum; __syncthreads();
    for (int off = 128; off > 0; off >>= 1) { if (t < off) red[t] += red[t + off]; __syncthreads(); }
    float mean = red[0] * (1.0f / H);
    __syncthreads();
    float vs = 0.f;
    for (int i = 0; i < 3; ++i) { float d = vals[i] - mean; vs += d * d; }
    red[t] = vs; __syncthreads();
    for (int off = 128; off > 0; off >>= 1) { if (t < off) red[t] += red[t + off]; __syncthreads(); }
    float inv = rsqrtf(red[0] * (1.0f / H) + LN_EPS);
    for (int i = 0; i < 3; ++i) {
        int c = t + i * 256;
        h[(size_t)row * H + c] = (vals[i] - mean) * inv * g[c] + bta[c];
    }
}

// ---------------- Generic fp32 GEMM: C = A(MxK) @ W(KxN) + bias, opt GELU ----------------
// 64x64 tile, 256 threads (16x16), each computes 4x4. K % 16 == 0, M % 64 == 0, N % 64 == 0.
template <int ACT>   // 0 = none, 1 = exact gelu
__global__ void gemm_kernel(const float* __restrict__ A,
                            const float* __restrict__ W,
                            const float* __restrict__ bias,
                            float* __restrict__ C,
                            int Mdim, int K, int N) {
    __shared__ float As[16][68];
    __shared__ float Bs[16][68];
    int tid = threadIdx.x;
    int tx = tid & 15, ty = tid >> 4;
    int ntiles = N >> 6;
    int bn = blockIdx.x % ntiles, bm = blockIdx.x / ntiles;
    int m0 = bm << 6, n0 = bn << 6;
    float acc[4][4] = {};
    for (int kt = 0; kt < K; kt += 16) {
        // A tile: 64 rows x 16 k
        for (int i = 0; i < 4; ++i) {
            int idx = tid * 4 + i;
            int r = idx >> 4, c = idx & 15;
            As[c][r] = A[(size_t)(m0 + r) * K + kt + c];
        }
        // B tile: 16 k x 64 n
        for (int i = 0; i < 4; ++i) {
            int idx = tid + i * 256;
            int r = idx >> 6, c = idx & 63;
            Bs[r][c] = W[(size_t)(kt + r) * N + n0 + c];
        }
        __syncthreads();
#pragma unroll
        for (int kk = 0; kk < 16; ++kk) {
            float a[4], bb[4];
#pragma unroll
            for (int i = 0; i < 4; ++i) a[i] = As[kk][ty * 4 + i];
#pragma unroll
            for (int j = 0; j < 4; ++j) bb[j] = Bs[kk][tx * 4 + j];
#pragma unroll
            for (int i = 0; i < 4; ++i)
#pragma unroll
                for (int j = 0; j < 4; ++j) acc[i][j] += a[i] * bb[j];
        }
        __syncthreads();
    }
    for (int i = 0; i < 4; ++i) {
        int row = m0 + ty * 4 + i;
        for (int j = 0; j < 4; ++j) {
            int col = n0 + tx * 4 + j;
            float v = acc[i][j] + bias[col];
            if (ACT == 1) v = 0.5f * v * (1.0f + erff(v * 0.70710678118654752f));
            C[(size_t)row * N + col] = v;
        }
    }
}

// ---------------- Fused attention: one block per (b, head, qrow) ----------------
__global__ void attn_kernel(const float* __restrict__ q,
                            const float* __restrict__ k,
                            const float* __restrict__ v,
                            float* __restrict__ ctx) {
    int blk = blockIdx.x;
    int qrow = blk % S;
    int bh = blk / S;
    int hh = bh % NH;
    int b = bh / NH;
    int t = threadIdx.x;   // 256 = S
    __shared__ float qs[DH];
    __shared__ float p[S];
    __shared__ float red[256];
    const float* qptr = q + ((size_t)(b * S + qrow) * H) + hh * DH;
    if (t < DH) qs[t] = qptr[t];
    __syncthreads();
    const float* kptr = k + ((size_t)(b * S + t) * H) + hh * DH;
    float acc = 0.f;
#pragma unroll 16
    for (int d = 0; d < DH; ++d) acc += qs[d] * kptr[d];
    acc *= 0.125f;   // 1/sqrt(64)
    red[t] = acc; __syncthreads();
    for (int off = 128; off > 0; off >>= 1) { if (t < off) red[t] = fmaxf(red[t], red[t + off]); __syncthreads(); }
    float mx = red[0]; __syncthreads();
    float e = expf(acc - mx);
    p[t] = e;
    red[t] = e; __syncthreads();
    for (int off = 128; off > 0; off >>= 1) { if (t < off) red[t] += red[t + off]; __syncthreads(); }
    float inv = 1.0f / red[0];
    if (t < DH) {
        float acc2 = 0.f;
        for (int kk = 0; kk < S; ++kk)
            acc2 += p[kk] * v[((size_t)(b * S + kk) * H) + hh * DH + t];
        ctx[((size_t)(b * S + qrow) * H) + hh * DH + t] = acc2 * inv;
    }
}

// ---------------- Classifier: logits = h @ clf_W(768x9) + clf_b ----------------
__global__ void clf_kernel(const float* __restrict__ h,
                           const float* __restrict__ W,
                           const float* __restrict__ bias,
                           float* __restrict__ logits) {
    int row = blockIdx.x;
    int t = threadIdx.x;    // 256
    float acc[T] = {};
    for (int kk = t; kk < H; kk += 256) {
        float x = h[(size_t)row * H + kk];
#pragma unroll
        for (int n = 0; n < T; ++n) acc[n] += x * W[kk * T + n];
    }
    __shared__ float red[256][T];
#pragma unroll
    for (int n = 0; n < T; ++n) red[t][n] = acc[n];
    __syncthreads();
    for (int off = 128; off > 0; off >>= 1) {
        if (t < off)
            for (int n = 0; n < T; ++n) red[t][n] += red[t + off][n];
        __syncthreads();
    }
    if (t < T) logits[(size_t)row * T + t] = red[0][t] + bias[t];
}

// ---------------- CRF: numerator + forward-algorithm denominator ----------------
__global__ void crf_kernel(const float* __restrict__ logits,
                           const int* __restrict__ target,
                           const float* __restrict__ start,
                           const float* __restrict__ trans,
                           const float* __restrict__ endv,
                           float* __restrict__ llh) {
    int b = blockIdx.x;
    int t = threadIdx.x;   // 64 threads (one wave)
    __shared__ float alpha[T], alpha2[T];
    __shared__ float trs[T * T];
    __shared__ float numsh;
    for (int i = t; i < T * T; i += 64) trs[i] = trans[i];
    const float* lg = logits + (size_t)b * S * T;
    const int* tg = target + b * S;

    if (t == 0) {
        bool m0 = tg[0] > -1;
        int tag0 = m0 ? tg[0] : 0;
        float num = start[tag0] + lg[tag0];
        int cnt = m0 ? 1 : 0;
        int ptag = tag0;
        for (int s = 1; s < S; ++s) {
            bool m = tg[s] > -1;
            int tag = m ? tg[s] : 0;
            float e = lg[s * T + tag];
            float tr = trans[ptag * T + tag];
            if (m) { num += tr + e; cnt += 1; }
            ptag = tag;
        }
        int lastIdx = cnt - 1;
        if (lastIdx < 0) lastIdx = 0;
        int lastTag = (tg[lastIdx] > -1) ? tg[lastIdx] : 0;
        num += endv[lastTag];
        numsh = num;
    }
    if (t < T) alpha[t] = start[t] + lg[t];
    __syncthreads();

    for (int s = 1; s < S; ++s) {
        bool m = tg[s] > -1;
        if (t < T) {
            float mx = -1e30f;
#pragma unroll
            for (int i = 0; i < T; ++i) mx = fmaxf(mx, alpha[i] + trs[i * T + t]);
            float sum = 0.f;
#pragma unroll
            for (int i = 0; i < T; ++i) sum += expf(alpha[i] + trs[i * T + t] - mx);
            float nxt = logf(sum) + mx + lg[s * T + t];
            alpha2[t] = m ? nxt : alpha[t];
        }
        __syncthreads();
        if (t < T) alpha[t] = alpha2[t];
        __syncthreads();
    }
    if (t == 0) {
        float mx = -1e30f;
        for (int i = 0; i < T; ++i) mx = fmaxf(mx, alpha[i] + endv[i]);
        float sum = 0.f;
        for (int i = 0; i < T; ++i) sum += expf(alpha[i] + endv[i] - mx);
        float denom = logf(sum) + mx;
        llh[b] = numsh - denom;
    }
}

__global__ void final_kernel(const float* __restrict__ llh, float* __restrict__ out) {
    if (threadIdx.x == 0) {
        float s = 0.f;
        for (int b = 0; b < B; ++b) s += llh[b];
        out[0] = -s / B;
    }
}

// ---------------- Host launch ----------------
extern "C" void kernel_launch(void* const* d_in, const int* in_sizes, int n_in,
                              void* d_out, int out_size, void* d_ws, size_t ws_size,
                              hipStream_t stream) {
    const int*   x        = (const int*)d_in[0];
    const int*   target   = (const int*)d_in[1];
    const float* word_emb = (const float*)d_in[2];
    const float* pos_emb  = (const float*)d_in[3];
    const float* type_emb = (const float*)d_in[4];
    const float* emb_ln_g = (const float*)d_in[5];
    const float* emb_ln_b = (const float*)d_in[6];
    const float* Wq = (const float*)d_in[7];
    const float* bq = (const float*)d_in[8];
    const float* Wk = (const float*)d_in[9];
    const float* bk = (const float*)d_in[10];
    const float* Wv = (const float*)d_in[11];
    const float* bv = (const float*)d_in[12];
    const float* Wo = (const float*)d_in[13];
    const float* bo = (const float*)d_in[14];
    const float* ln1_g = (const float*)d_in[15];
    const float* ln1_b = (const float*)d_in[16];
    const float* W1 = (const float*)d_in[17];
    const float* b1 = (const float*)d_in[18];
    const float* W2 = (const float*)d_in[19];
    const float* b2 = (const float*)d_in[20];
    const float* ln2_g = (const float*)d_in[21];
    const float* ln2_b = (const float*)d_in[22];
    const float* clf_W = (const float*)d_in[23];
    const float* clf_b = (const float*)d_in[24];
    const float* crf_start = (const float*)d_in[25];
    const float* crf_trans = (const float*)d_in[26];
    const float* crf_end   = (const float*)d_in[27];

    char* ws = (char*)d_ws;
    size_t off = 0;
    auto alloc = [&](size_t bytes) { void* p = ws + off; off += (bytes + 255) & ~255ull; return p; };
    float* h      = (float*)alloc((size_t)M * H * 4);
    float* qb     = (float*)alloc((size_t)M * H * 4);
    float* kb     = (float*)alloc((size_t)M * H * 4);
    float* vb     = (float*)alloc((size_t)M * H * 4);
    float* tmp    = (float*)alloc((size_t)M * H * 4);
    float* ff     = (float*)alloc((size_t)M * DFF * 4);
    float* logits = (float*)alloc((size_t)M * T * 4);
    float* llh    = (float*)alloc((size_t)B * 4);

    embed_ln_kernel<<<M, 256, 0, stream>>>(x, word_emb, pos_emb, type_emb, emb_ln_g, emb_ln_b, h);

    const int gH  = (M / 64) * (H / 64);     // 768 blocks
    const int gFF = (M / 64) * (DFF / 64);   // 3072 blocks

    for (int l = 0; l < L; ++l) {
        const size_t wofs = (size_t)l * H * H;
        gemm_kernel<0><<<gH, 256, 0, stream>>>(h, Wq + wofs, bq + l * H, qb, M, H, H);
        gemm_kernel<0><<<gH, 256, 0, stream>>>(h, Wk + wofs, bk + l * H, kb, M, H, H);
        gemm_kernel<0><<<gH, 256, 0, stream>>>(h, Wv + wofs, bv + l * H, vb, M, H, H);
        attn_kernel<<<B * NH * S, 256, 0, stream>>>(qb, kb, vb, tmp);
        gemm_kernel<0><<<gH, 256, 0, stream>>>(tmp, Wo + wofs, bo + l * H, qb, M, H, H);
        residual_ln_kernel<<<M, 256, 0, stream>>>(h, qb, ln1_g + l * H, ln1_b + l * H);
        gemm_kernel<1><<<gFF, 256, 0, stream>>>(h, W1 + (size_t)l * H * DFF, b1 + l * DFF, ff, M, H, DFF);
        gemm_kernel<0><<<gH, 256, 0, stream>>>(ff, W2 + (size_t)l * DFF * H, b2 + l * H, qb, M, DFF, H);
        residual_ln_kernel<<<M, 256, 0, stream>>>(h, qb, ln2_g + l * H, ln2_b + l * H);
    }

    clf_kernel<<<M, 256, 0, stream>>>(h, clf_W, clf_b, logits);
    crf_kernel<<<B, 64, 0, stream>>>(logits, target, crf_start, crf_trans, crf_end, llh);
    final_kernel<<<1, 64, 0, stream>>>(llh, (float*)d_out);
}

// Round 2
// 8519.443 us; speedup vs baseline: 1.8820x; 1.8820x over previous
//
#include <hip/hip_runtime.h>
#include <math.h>

#define B 16
#define S 256
#define H 768
#define NH 12
#define DH 64
#define DFF 3072
#define L 12
#define T 9
#define M (B*S)
#define LN_EPS 1e-12f

typedef __attribute__((ext_vector_type(8))) __bf16 bf16x8;
typedef __attribute__((ext_vector_type(8))) unsigned short u16x8;
typedef __attribute__((ext_vector_type(4))) float f32x4;

__device__ __forceinline__ unsigned short f2bf(float f) {
    unsigned int u = __float_as_uint(f);
    unsigned int r = u + 0x7fffu + ((u >> 16) & 1u);
    return (unsigned short)(r >> 16);
}
__device__ __forceinline__ float bf2f(unsigned short h) {
    return __uint_as_float((unsigned int)h << 16);
}

// ---------------- Weight convert + transpose: W (K x N) f32 -> WT (N x K) bf16 ----------------
__global__ void convT_kernel(const float* __restrict__ W, unsigned short* __restrict__ WT,
                             int K, int N) {
    __shared__ float tile[32][33];
    const int layer = blockIdx.z;
    const float* Wp = W + (size_t)layer * K * N;
    unsigned short* Tp = WT + (size_t)layer * K * N;
    const int n0 = blockIdx.x * 32, k0 = blockIdx.y * 32;
    const int tx = threadIdx.x, ty = threadIdx.y;  // 32 x 8
#pragma unroll
    for (int i = 0; i < 32; i += 8)
        tile[ty + i][tx] = Wp[(size_t)(k0 + ty + i) * N + n0 + tx];
    __syncthreads();
#pragma unroll
    for (int i = 0; i < 32; i += 8)
        Tp[(size_t)(n0 + ty + i) * K + k0 + tx] = f2bf(tile[tx][ty + i]);
}

// ---------------- Embedding + LayerNorm (writes f32 h and bf16 hb) ----------------
__global__ void embed_ln_kernel(const int* __restrict__ x,
                                const float* __restrict__ word_emb,
                                const float* __restrict__ pos_emb,
                                const float* __restrict__ type_emb,
                                const float* __restrict__ g,
                                const float* __restrict__ bta,
                                float* __restrict__ h,
                                unsigned short* __restrict__ hb) {
    int row = blockIdx.x;
    int s = row % S;
    int tok = x[row];
    int t = threadIdx.x;
    float vals[3];
    float sum = 0.f;
    for (int i = 0; i < 3; ++i) {
        int c = t + i * 256;
        float val = word_emb[(size_t)tok * H + c] + pos_emb[s * H + c] + type_emb[c];
        vals[i] = val; sum += val;
    }
    __shared__ float red[256];
    red[t] = sum; __syncthreads();
    for (int off = 128; off > 0; off >>= 1) { if (t < off) red[t] += red[t + off]; __syncthreads(); }
    float mean = red[0] * (1.0f / H);
    __syncthreads();
    float vs = 0.f;
    for (int i = 0; i < 3; ++i) { float d = vals[i] - mean; vs += d * d; }
    red[t] = vs; __syncthreads();
    for (int off = 128; off > 0; off >>= 1) { if (t < off) red[t] += red[t + off]; __syncthreads(); }
    float inv = rsqrtf(red[0] * (1.0f / H) + LN_EPS);
    for (int i = 0; i < 3; ++i) {
        int c = t + i * 256;
        float o = (vals[i] - mean) * inv * g[c] + bta[c];
        h[(size_t)row * H + c] = o;
        hb[(size_t)row * H + c] = f2bf(o);
    }
}

// ---------------- Residual + LayerNorm (in-place on h, also writes bf16 hb) ----------------
__global__ void residual_ln_kernel(float* __restrict__ h,
                                   const float* __restrict__ delta,
                                   const float* __restrict__ g,
                                   const float* __restrict__ bta,
                                   unsigned short* __restrict__ hb) {
    int row = blockIdx.x;
    int t = threadIdx.x;
    float vals[3];
    float sum = 0.f;
    for (int i = 0; i < 3; ++i) {
        int c = t + i * 256;
        float val = h[(size_t)row * H + c] + delta[(size_t)row * H + c];
        vals[i] = val; sum += val;
    }
    __shared__ float red[256];
    red[t] = sum; __syncthreads();
    for (int off = 128; off > 0; off >>= 1) { if (t < off) red[t] += red[t + off]; __syncthreads(); }
    float mean = red[0] * (1.0f / H);
    __syncthreads();
    float vs = 0.f;
    for (int i = 0; i < 3; ++i) { float d = vals[i] - mean; vs += d * d; }
    red[t] = vs; __syncthreads();
    for (int off = 128; off > 0; off >>= 1) { if (t < off) red[t] += red[t + off]; __syncthreads(); }
    float inv = rsqrtf(red[0] * (1.0f / H) + LN_EPS);
    for (int i = 0; i < 3; ++i) {
        int c = t + i * 256;
        float o = (vals[i] - mean) * inv * g[c] + bta[c];
        h[(size_t)row * H + c] = o;
        hb[(size_t)row * H + c] = f2bf(o);
    }
}

// ---------------- bf16 MFMA GEMM: C = A(MxK) @ WT^T + bias ----------------
// A: MxK bf16 row-major. WT: NxK bf16 row-major (pre-transposed weight).
// 128x128 tile, 4 waves (2x2), each wave 64x64 = 4x4 fragments of 16x16x32.
// LDS row stride 56 ushorts (32 data + 24 pad): 16B-aligned rows, 2-way-free banks.
#define LSTR 56

template<int ACT, int WF, int WB>
__global__ __launch_bounds__(256, 2)
void gemm_bf16(const unsigned short* __restrict__ A,
               const unsigned short* __restrict__ WT,
               const float* __restrict__ bias,
               float* __restrict__ Cf,
               unsigned short* __restrict__ Cb,
               int K, int N) {
    __shared__ unsigned short lA[128 * LSTR];
    __shared__ unsigned short lB[128 * LSTR];
    const int tid = threadIdx.x;
    const int m0 = blockIdx.y << 7, n0 = blockIdx.x << 7;
    const int l = tid & 63, w = tid >> 6;
    const int wr = w >> 1, wc = w & 1;
    const int lr = l & 15, kg = l >> 4;

    // staging: thread covers 8 bf16 (16B) at row=tid>>2 (+64), col=(tid&3)*8
    const int srow = tid >> 2, scol = (tid & 3) << 3;
    const unsigned short* gA0 = A + (size_t)(m0 + srow) * K + scol;
    const unsigned short* gA1 = gA0 + (size_t)64 * K;
    const unsigned short* gB0 = WT + (size_t)(n0 + srow) * K + scol;
    const unsigned short* gB1 = gB0 + (size_t)64 * K;
    u16x8* sA0 = (u16x8*)&lA[srow * LSTR + scol];
    u16x8* sA1 = (u16x8*)&lA[(srow + 64) * LSTR + scol];
    u16x8* sB0 = (u16x8*)&lB[srow * LSTR + scol];
    u16x8* sB1 = (u16x8*)&lB[(srow + 64) * LSTR + scol];

    f32x4 acc[4][4];
#pragma unroll
    for (int i = 0; i < 4; ++i)
#pragma unroll
        for (int j = 0; j < 4; ++j) acc[i][j] = (f32x4){0.f, 0.f, 0.f, 0.f};

    u16x8 ra0 = *(const u16x8*)gA0;
    u16x8 ra1 = *(const u16x8*)gA1;
    u16x8 rb0 = *(const u16x8*)gB0;
    u16x8 rb1 = *(const u16x8*)gB1;

    for (int kt = 0; kt < K; kt += 32) {
        *sA0 = ra0; *sA1 = ra1; *sB0 = rb0; *sB1 = rb1;
        __syncthreads();
        if (kt + 32 < K) {  // prefetch next K-tile; overlaps with MFMA below
            ra0 = *(const u16x8*)(gA0 + kt + 32);
            ra1 = *(const u16x8*)(gA1 + kt + 32);
            rb0 = *(const u16x8*)(gB0 + kt + 32);
            rb1 = *(const u16x8*)(gB1 + kt + 32);
        }
        bf16x8 af[4], bfr[4];
#pragma unroll
        for (int m = 0; m < 4; ++m)
            af[m] = *(const bf16x8*)&lA[((wr << 6) + (m << 4) + lr) * LSTR + (kg << 3)];
#pragma unroll
        for (int n = 0; n < 4; ++n)
            bfr[n] = *(const bf16x8*)&lB[((wc << 6) + (n << 4) + lr) * LSTR + (kg << 3)];
#pragma unroll
        for (int m = 0; m < 4; ++m)
#pragma unroll
            for (int n = 0; n < 4; ++n)
                acc[m][n] = __builtin_amdgcn_mfma_f32_16x16x32_bf16(af[m], bfr[n], acc[m][n], 0, 0, 0);
        __syncthreads();
    }

    // C/D layout: col = lane&15, row = (lane>>4)*4 + j  [measured m89/m91]
    const int rbase = m0 + (wr << 6) + ((l >> 4) << 2);
    const int cbase = n0 + (wc << 6) + (l & 15);
#pragma unroll
    for (int m = 0; m < 4; ++m) {
#pragma unroll
        for (int n = 0; n < 4; ++n) {
            const int col = cbase + (n << 4);
            const float bv = bias[col];
#pragma unroll
            for (int j = 0; j < 4; ++j) {
                const int row = rbase + (m << 4) + j;
                float v = acc[m][n][j] + bv;
                if (ACT == 1) v = 0.5f * v * (1.0f + erff(v * 0.70710678118654752440f));
                if (WF) Cf[(size_t)row * N + col] = v;
                if (WB) Cb[(size_t)row * N + col] = f2bf(v);
            }
        }
    }
}

// ---------------- Tiled attention: block = (b, head, 64-q-chunk), 256 threads ----------------
__global__ __launch_bounds__(256, 2)
void attn_bf16(const unsigned short* __restrict__ qb,
               const unsigned short* __restrict__ kb,
               const unsigned short* __restrict__ vb,
               unsigned short* __restrict__ ctxb) {
    __shared__ unsigned short Ks[S][65];
    __shared__ unsigned short Vs[S][65];
    __shared__ float qsh[DH];
    __shared__ float p[S];
    __shared__ float wred[8];
    __shared__ float part[4][DH];

    const int blk = blockIdx.x;
    const int qc = blk & 3;
    const int hh = (blk >> 2) % NH;
    const int b = blk / (4 * NH);
    const int t = threadIdx.x;
    const int lane = t & 63, w = t >> 6;

    {   // stage K,V (bf16): 256 rows x 64 d
        int r = t >> 3, c = (t & 7) << 3;
        for (int it = 0; it < 8; ++it, r += 32) {
            size_t goff = ((size_t)(b * S + r)) * H + hh * DH + c;
            u16x8 kv = *(const u16x8*)&kb[goff];
            u16x8 vv = *(const u16x8*)&vb[goff];
#pragma unroll
            for (int j = 0; j < 8; ++j) { Ks[r][c + j] = kv[j]; Vs[r][c + j] = vv[j]; }
        }
    }
    __syncthreads();

    for (int qr = 0; qr < 64; ++qr) {
        const int qrow = (qc << 6) + qr;
        if (t < DH) qsh[t] = bf2f(qb[((size_t)(b * S + qrow)) * H + hh * DH + t]);
        __syncthreads();
        float sc = 0.f;
#pragma unroll
        for (int d = 0; d < DH; ++d) sc += qsh[d] * bf2f(Ks[t][d]);
        sc *= 0.125f;
        float mx = sc;
#pragma unroll
        for (int o = 32; o; o >>= 1) mx = fmaxf(mx, __shfl_xor(mx, o));
        if (lane == 0) wred[w] = mx;
        __syncthreads();
        mx = fmaxf(fmaxf(wred[0], wred[1]), fmaxf(wred[2], wred[3]));
        float e = expf(sc - mx);
        p[t] = e;
        float sm = e;
#pragma unroll
        for (int o = 32; o; o >>= 1) sm += __shfl_xor(sm, o);
        if (lane == 0) wred[4 + w] = sm;
        __syncthreads();
        const float inv = 1.f / (wred[4] + wred[5] + wred[6] + wred[7]);
        float acc = 0.f;
#pragma unroll
        for (int kk = 0; kk < 64; ++kk)
            acc += p[(w << 6) + kk] * bf2f(Vs[(w << 6) + kk][lane]);
        part[w][lane] = acc;
        __syncthreads();
        if (t < DH) {
            float c4 = (part[0][t] + part[1][t] + part[2][t] + part[3][t]) * inv;
            ctxb[((size_t)(b * S + qrow)) * H + hh * DH + t] = f2bf(c4);
        }
        __syncthreads();
    }
}

// ---------------- Classifier: logits = h @ clf_W(768x9) + clf_b ----------------
__global__ void clf_kernel(const float* __restrict__ h,
                           const float* __restrict__ W,
                           const float* __restrict__ bias,
                           float* __restrict__ logits) {
    int row = blockIdx.x;
    int t = threadIdx.x;
    float acc[T] = {};
    for (int kk = t; kk < H; kk += 256) {
        float x = h[(size_t)row * H + kk];
#pragma unroll
        for (int n = 0; n < T; ++n) acc[n] += x * W[kk * T + n];
    }
    __shared__ float red[256][T];
#pragma unroll
    for (int n = 0; n < T; ++n) red[t][n] = acc[n];
    __syncthreads();
    for (int off = 128; off > 0; off >>= 1) {
        if (t < off)
            for (int n = 0; n < T; ++n) red[t][n] += red[t + off][n];
        __syncthreads();
    }
    if (t < T) logits[(size_t)row * T + t] = red[0][t] + bias[t];
}

// ---------------- CRF ----------------
__global__ void crf_kernel(const float* __restrict__ logits,
                           const int* __restrict__ target,
                           const float* __restrict__ start,
                           const float* __restrict__ trans,
                           const float* __restrict__ endv,
                           float* __restrict__ llh) {
    int b = blockIdx.x;
    int t = threadIdx.x;
    __shared__ float alpha[T], alpha2[T];
    __shared__ float trs[T * T];
    __shared__ float numsh;
    for (int i = t; i < T * T; i += 64) trs[i] = trans[i];
    const float* lg = logits + (size_t)b * S * T;
    const int* tg = target + b * S;

    if (t == 0) {
        bool m0 = tg[0] > -1;
        int tag0 = m0 ? tg[0] : 0;
        float num = start[tag0] + lg[tag0];
        int cnt = m0 ? 1 : 0;
        int ptag = tag0;
        for (int s = 1; s < S; ++s) {
            bool m = tg[s] > -1;
            int tag = m ? tg[s] : 0;
            float e = lg[s * T + tag];
            float tr = trans[ptag * T + tag];
            if (m) { num += tr + e; cnt += 1; }
            ptag = tag;
        }
        int lastIdx = cnt - 1;
        if (lastIdx < 0) lastIdx = 0;
        int lastTag = (tg[lastIdx] > -1) ? tg[lastIdx] : 0;
        num += endv[lastTag];
        numsh = num;
    }
    if (t < T) alpha[t] = start[t] + lg[t];
    __syncthreads();

    for (int s = 1; s < S; ++s) {
        bool m = tg[s] > -1;
        if (t < T) {
            float mx = -1e30f;
#pragma unroll
            for (int i = 0; i < T; ++i) mx = fmaxf(mx, alpha[i] + trs[i * T + t]);
            float sum = 0.f;
#pragma unroll
            for (int i = 0; i < T; ++i) sum += expf(alpha[i] + trs[i * T + t] - mx);
            float nxt = logf(sum) + mx + lg[s * T + t];
            alpha2[t] = m ? nxt : alpha[t];
        }
        __syncthreads();
        if (t < T) alpha[t] = alpha2[t];
        __syncthreads();
    }
    if (t == 0) {
        float mx = -1e30f;
        for (int i = 0; i < T; ++i) mx = fmaxf(mx, alpha[i] + endv[i]);
        float sum = 0.f;
        for (int i = 0; i < T; ++i) sum += expf(alpha[i] + endv[i] - mx);
        float denom = logf(sum) + mx;
        llh[b] = numsh - denom;
    }
}

__global__ void final_kernel(const float* __restrict__ llh, float* __restrict__ out) {
    if (threadIdx.x == 0) {
        float s = 0.f;
        for (int b = 0; b < B; ++b) s += llh[b];
        out[0] = -s / B;
    }
}

// ---------------- Host launch ----------------
extern "C" void kernel_launch(void* const* d_in, const int* in_sizes, int n_in,
                              void* d_out, int out_size, void* d_ws, size_t ws_size,
                              hipStream_t stream) {
    const int*   x        = (const int*)d_in[0];
    const int*   target   = (const int*)d_in[1];
    const float* word_emb = (const float*)d_in[2];
    const float* pos_emb  = (const float*)d_in[3];
    const float* type_emb = (const float*)d_in[4];
    const float* emb_ln_g = (const float*)d_in[5];
    const float* emb_ln_b = (const float*)d_in[6];
    const float* Wq = (const float*)d_in[7];
    const float* bq = (const float*)d_in[8];
    const float* Wk = (const float*)d_in[9];
    const float* bk = (const float*)d_in[10];
    const float* Wv = (const float*)d_in[11];
    const float* bv = (const float*)d_in[12];
    const float* Wo = (const float*)d_in[13];
    const float* bo = (const float*)d_in[14];
    const float* ln1_g = (const float*)d_in[15];
    const float* ln1_b = (const float*)d_in[16];
    const float* W1 = (const float*)d_in[17];
    const float* b1 = (const float*)d_in[18];
    const float* W2 = (const float*)d_in[19];
    const float* b2 = (const float*)d_in[20];
    const float* ln2_g = (const float*)d_in[21];
    const float* ln2_b = (const float*)d_in[22];
    const float* clf_W = (const float*)d_in[23];
    const float* clf_b = (const float*)d_in[24];
    const float* crf_start = (const float*)d_in[25];
    const float* crf_trans = (const float*)d_in[26];
    const float* crf_end   = (const float*)d_in[27];

    char* ws = (char*)d_ws;
    size_t off = 0;
    auto alloc = [&](size_t bytes) { void* p = ws + off; off += (bytes + 255) & ~255ull; return p; };

    unsigned short* wqT = (unsigned short*)alloc((size_t)L * H * H * 2);
    unsigned short* wkT = (unsigned short*)alloc((size_t)L * H * H * 2);
    unsigned short* wvT = (unsigned short*)alloc((size_t)L * H * H * 2);
    unsigned short* woT = (unsigned short*)alloc((size_t)L * H * H * 2);
    unsigned short* w1T = (unsigned short*)alloc((size_t)L * H * DFF * 2);
    unsigned short* w2T = (unsigned short*)alloc((size_t)L * H * DFF * 2);
    float*          h    = (float*)alloc((size_t)M * H * 4);
    unsigned short* hb   = (unsigned short*)alloc((size_t)M * H * 2);
    unsigned short* qbuf = (unsigned short*)alloc((size_t)M * H * 2);
    unsigned short* kbuf = (unsigned short*)alloc((size_t)M * H * 2);
    unsigned short* vbuf = (unsigned short*)alloc((size_t)M * H * 2);
    unsigned short* ctxb = (unsigned short*)alloc((size_t)M * H * 2);
    float*          go   = (float*)alloc((size_t)M * H * 4);
    unsigned short* ffb  = (unsigned short*)alloc((size_t)M * DFF * 2);
    float*          logits = (float*)alloc((size_t)M * T * 4);
    float*          llh    = (float*)alloc((size_t)B * 4);

    dim3 tb(32, 8);
    convT_kernel<<<dim3(H / 32, H / 32, L), tb, 0, stream>>>(Wq, wqT, H, H);
    convT_kernel<<<dim3(H / 32, H / 32, L), tb, 0, stream>>>(Wk, wkT, H, H);
    convT_kernel<<<dim3(H / 32, H / 32, L), tb, 0, stream>>>(Wv, wvT, H, H);
    convT_kernel<<<dim3(H / 32, H / 32, L), tb, 0, stream>>>(Wo, woT, H, H);
    convT_kernel<<<dim3(DFF / 32, H / 32, L), tb, 0, stream>>>(W1, w1T, H, DFF);
    convT_kernel<<<dim3(H / 32, DFF / 32, L), tb, 0, stream>>>(W2, w2T, DFF, H);

    embed_ln_kernel<<<M, 256, 0, stream>>>(x, word_emb, pos_emb, type_emb, emb_ln_g, emb_ln_b, h, hb);

    const dim3 gH(H / 128, M / 128);     // 6 x 32
    const dim3 gFF(DFF / 128, M / 128);  // 24 x 32

    for (int l = 0; l < L; ++l) {
        const size_t wofs = (size_t)l * H * H;
        const size_t fofs = (size_t)l * H * DFF;
        gemm_bf16<0, 0, 1><<<gH, 256, 0, stream>>>(hb, wqT + wofs, bq + l * H, nullptr, qbuf, H, H);
        gemm_bf16<0, 0, 1><<<gH, 256, 0, stream>>>(hb, wkT + wofs, bk + l * H, nullptr, kbuf, H, H);
        gemm_bf16<0, 0, 1><<<gH, 256, 0, stream>>>(hb, wvT + wofs, bv + l * H, nullptr, vbuf, H, H);
        attn_bf16<<<B * NH * 4, 256, 0, stream>>>(qbuf, kbuf, vbuf, ctxb);
        gemm_bf16<0, 1, 0><<<gH, 256, 0, stream>>>(ctxb, woT + wofs, bo + l * H, go, nullptr, H, H);
        residual_ln_kernel<<<M, 256, 0, stream>>>(h, go, ln1_g + l * H, ln1_b + l * H, hb);
        gemm_bf16<1, 0, 1><<<gFF, 256, 0, stream>>>(hb, w1T + fofs, b1 + l * DFF, nullptr, ffb, H, DFF);
        gemm_bf16<0, 1, 0><<<gH, 256, 0, stream>>>(ffb, w2T + fofs, b2 + l * H, go, nullptr, DFF, H);
        residual_ln_kernel<<<M, 256, 0, stream>>>(h, go, ln2_g + l * H, ln2_b + l * H, hb);
    }

    clf_kernel<<<M, 256, 0, stream>>>(h, clf_W, clf_b, logits);
    crf_kernel<<<B, 64, 0, stream>>>(logits, target, crf_start, crf_trans, crf_end, llh);
    final_kernel<<<1, 64, 0, stream>>>(llh, (float*)d_out);
}

// Round 3
// 2543.166 us; speedup vs baseline: 6.3046x; 3.3499x over previous
//
#include <hip/hip_runtime.h>
#include <math.h>

#define B 16
#define S 256
#define H 768
#define NH 12
#define DH 64
#define DFF 3072
#define L 12
#define T 9
#define M (B*S)
#define LN_EPS 1e-12f
#define QKVS (3*H)

typedef __attribute__((ext_vector_type(8))) __bf16 bf16x8;
typedef __attribute__((ext_vector_type(8))) unsigned short u16x8;
typedef __attribute__((ext_vector_type(4))) float f32x4;

__device__ __forceinline__ unsigned short f2bf(float f) {
    unsigned int u = __float_as_uint(f);
    unsigned int r = u + 0x7fffu + ((u >> 16) & 1u);
    return (unsigned short)(r >> 16);
}
__device__ __forceinline__ float bf2f(unsigned short h) {
    return __uint_as_float((unsigned int)h << 16);
}

// ---------------- Weight convert + transpose: W (K x N) f32 -> WT (N x K) bf16 ----------------
__global__ void convT_kernel(const float* __restrict__ W, unsigned short* __restrict__ WT,
                             int K, int N, size_t dstLayerStride) {
    __shared__ float tile[32][33];
    const int layer = blockIdx.z;
    const float* Wp = W + (size_t)layer * K * N;
    unsigned short* Tp = WT + (size_t)layer * dstLayerStride;
    const int n0 = blockIdx.x * 32, k0 = blockIdx.y * 32;
    const int tx = threadIdx.x, ty = threadIdx.y;  // 32 x 8
#pragma unroll
    for (int i = 0; i < 32; i += 8)
        tile[ty + i][tx] = Wp[(size_t)(k0 + ty + i) * N + n0 + tx];
    __syncthreads();
#pragma unroll
    for (int i = 0; i < 32; i += 8)
        Tp[(size_t)(n0 + ty + i) * K + k0 + tx] = f2bf(tile[tx][ty + i]);
}

// ---------------- Concat QKV biases per layer: [L][2304] ----------------
__global__ void biascat_kernel(const float* __restrict__ bq, const float* __restrict__ bk,
                               const float* __restrict__ bv, float* __restrict__ out) {
    int idx = blockIdx.x * 256 + threadIdx.x;
    if (idx >= L * QKVS) return;
    int l = idx / QKVS, c = idx % QKVS;
    float v = (c < H) ? bq[l * H + c] : (c < 2 * H) ? bk[l * H + c - H] : bv[l * H + c - 2 * H];
    out[idx] = v;
}

// ---------------- Embedding + LayerNorm (writes f32 h and bf16 hb) ----------------
__global__ void embed_ln_kernel(const int* __restrict__ x,
                                const float* __restrict__ word_emb,
                                const float* __restrict__ pos_emb,
                                const float* __restrict__ type_emb,
                                const float* __restrict__ g,
                                const float* __restrict__ bta,
                                float* __restrict__ h,
                                unsigned short* __restrict__ hb) {
    int row = blockIdx.x;
    int s = row % S;
    int tok = x[row];
    int t = threadIdx.x;
    float vals[3];
    float sum = 0.f;
    for (int i = 0; i < 3; ++i) {
        int c = t + i * 256;
        float val = word_emb[(size_t)tok * H + c] + pos_emb[s * H + c] + type_emb[c];
        vals[i] = val; sum += val;
    }
    __shared__ float red[256];
    red[t] = sum; __syncthreads();
    for (int off = 128; off > 0; off >>= 1) { if (t < off) red[t] += red[t + off]; __syncthreads(); }
    float mean = red[0] * (1.0f / H);
    __syncthreads();
    float vs = 0.f;
    for (int i = 0; i < 3; ++i) { float d = vals[i] - mean; vs += d * d; }
    red[t] = vs; __syncthreads();
    for (int off = 128; off > 0; off >>= 1) { if (t < off) red[t] += red[t + off]; __syncthreads(); }
    float inv = rsqrtf(red[0] * (1.0f / H) + LN_EPS);
    for (int i = 0; i < 3; ++i) {
        int c = t + i * 256;
        float o = (vals[i] - mean) * inv * g[c] + bta[c];
        h[(size_t)row * H + c] = o;
        hb[(size_t)row * H + c] = f2bf(o);
    }
}

// ---------------- Residual + LayerNorm (in-place on h, also writes bf16 hb) ----------------
__global__ void residual_ln_kernel(float* __restrict__ h,
                                   const float* __restrict__ delta,
                                   const float* __restrict__ g,
                                   const float* __restrict__ bta,
                                   unsigned short* __restrict__ hb) {
    int row = blockIdx.x;
    int t = threadIdx.x;
    float vals[3];
    float sum = 0.f;
    for (int i = 0; i < 3; ++i) {
        int c = t + i * 256;
        float val = h[(size_t)row * H + c] + delta[(size_t)row * H + c];
        vals[i] = val; sum += val;
    }
    __shared__ float red[256];
    red[t] = sum; __syncthreads();
    for (int off = 128; off > 0; off >>= 1) { if (t < off) red[t] += red[t + off]; __syncthreads(); }
    float mean = red[0] * (1.0f / H);
    __syncthreads();
    float vs = 0.f;
    for (int i = 0; i < 3; ++i) { float d = vals[i] - mean; vs += d * d; }
    red[t] = vs; __syncthreads();
    for (int off = 128; off > 0; off >>= 1) { if (t < off) red[t] += red[t + off]; __syncthreads(); }
    float inv = rsqrtf(red[0] * (1.0f / H) + LN_EPS);
    for (int i = 0; i < 3; ++i) {
        int c = t + i * 256;
        float o = (vals[i] - mean) * inv * g[c] + bta[c];
        h[(size_t)row * H + c] = o;
        hb[(size_t)row * H + c] = f2bf(o);
    }
}

// ---------------- bf16 MFMA GEMM: C = A(MxK) @ WT^T + bias ----------------
#define LSTR 56

template<int ACT, int WF, int WB>
__global__ __launch_bounds__(256, 2)
void gemm_bf16(const unsigned short* __restrict__ A,
               const unsigned short* __restrict__ WT,
               const float* __restrict__ bias,
               float* __restrict__ Cf,
               unsigned short* __restrict__ Cb,
               int K, int N) {
    __shared__ unsigned short lA[128 * LSTR];
    __shared__ unsigned short lB[128 * LSTR];
    const int tid = threadIdx.x;
    const int m0 = blockIdx.y << 7, n0 = blockIdx.x << 7;
    const int l = tid & 63, w = tid >> 6;
    const int wr = w >> 1, wc = w & 1;
    const int lr = l & 15, kg = l >> 4;

    const int srow = tid >> 2, scol = (tid & 3) << 3;
    const unsigned short* gA0 = A + (size_t)(m0 + srow) * K + scol;
    const unsigned short* gA1 = gA0 + (size_t)64 * K;
    const unsigned short* gB0 = WT + (size_t)(n0 + srow) * K + scol;
    const unsigned short* gB1 = gB0 + (size_t)64 * K;
    u16x8* sA0 = (u16x8*)&lA[srow * LSTR + scol];
    u16x8* sA1 = (u16x8*)&lA[(srow + 64) * LSTR + scol];
    u16x8* sB0 = (u16x8*)&lB[srow * LSTR + scol];
    u16x8* sB1 = (u16x8*)&lB[(srow + 64) * LSTR + scol];

    f32x4 acc[4][4];
#pragma unroll
    for (int i = 0; i < 4; ++i)
#pragma unroll
        for (int j = 0; j < 4; ++j) acc[i][j] = (f32x4){0.f, 0.f, 0.f, 0.f};

    u16x8 ra0 = *(const u16x8*)gA0;
    u16x8 ra1 = *(const u16x8*)gA1;
    u16x8 rb0 = *(const u16x8*)gB0;
    u16x8 rb1 = *(const u16x8*)gB1;

    for (int kt = 0; kt < K; kt += 32) {
        *sA0 = ra0; *sA1 = ra1; *sB0 = rb0; *sB1 = rb1;
        __syncthreads();
        if (kt + 32 < K) {
            ra0 = *(const u16x8*)(gA0 + kt + 32);
            ra1 = *(const u16x8*)(gA1 + kt + 32);
            rb0 = *(const u16x8*)(gB0 + kt + 32);
            rb1 = *(const u16x8*)(gB1 + kt + 32);
        }
        bf16x8 af[4], bfr[4];
#pragma unroll
        for (int m = 0; m < 4; ++m)
            af[m] = *(const bf16x8*)&lA[((wr << 6) + (m << 4) + lr) * LSTR + (kg << 3)];
#pragma unroll
        for (int n = 0; n < 4; ++n)
            bfr[n] = *(const bf16x8*)&lB[((wc << 6) + (n << 4) + lr) * LSTR + (kg << 3)];
#pragma unroll
        for (int m = 0; m < 4; ++m)
#pragma unroll
            for (int n = 0; n < 4; ++n)
                acc[m][n] = __builtin_amdgcn_mfma_f32_16x16x32_bf16(af[m], bfr[n], acc[m][n], 0, 0, 0);
        __syncthreads();
    }

    const int rbase = m0 + (wr << 6) + ((l >> 4) << 2);
    const int cbase = n0 + (wc << 6) + (l & 15);
#pragma unroll
    for (int m = 0; m < 4; ++m) {
#pragma unroll
        for (int n = 0; n < 4; ++n) {
            const int col = cbase + (n << 4);
            const float bv = bias[col];
#pragma unroll
            for (int j = 0; j < 4; ++j) {
                const int row = rbase + (m << 4) + j;
                float v = acc[m][n][j] + bv;
                if (ACT == 1) v = 0.5f * v * (1.0f + erff(v * 0.70710678118654752440f));
                if (WF) Cf[(size_t)row * N + col] = v;
                if (WB) Cb[(size_t)row * N + col] = f2bf(v);
            }
        }
    }
}

// ---------------- V transpose: qkv[.., 2H + h*64 + d] -> vtg[b*NH+h][d][s] ----------------
__global__ void vtrans_kernel(const unsigned short* __restrict__ qkv,
                              unsigned short* __restrict__ vtg) {
    __shared__ unsigned short tile[64 * 264];
    const int bh = blockIdx.x;
    const int b = bh / NH, hh = bh % NH;
    const int t = threadIdx.x;
    {
        const int d0 = (t & 7) << 3;
        int s = t >> 3;
#pragma unroll
        for (int it = 0; it < 8; ++it, s += 32) {
            u16x8 v = *(const u16x8*)&qkv[(size_t)(b * S + s) * QKVS + 2 * H + hh * 64 + d0];
#pragma unroll
            for (int j = 0; j < 8; ++j) {
                int d = d0 + j;
                tile[d * 264 + (s ^ (((d >> 3) & 7) << 3))] = v[j];  // swizzled -> conflict-free
            }
        }
    }
    __syncthreads();
    {
        const int s0 = (t & 31) << 3;
        int d = t >> 5;
#pragma unroll
        for (int it = 0; it < 8; ++it, d += 8) {
            int sp = s0 ^ (((d >> 3) & 7) << 3);
            u16x8 v = *(const u16x8*)&tile[d * 264 + sp];
            *(u16x8*)&vtg[(size_t)bh * (64 * 256) + d * 256 + s0] = v;
        }
    }
}

// ---------------- MFMA attention: block = (b, h, 64-q-chunk), 4 waves x 16 q-rows ----------------
__global__ __launch_bounds__(256, 2)
void attn_mfma(const unsigned short* __restrict__ qkv,
               const unsigned short* __restrict__ vtg,
               unsigned short* __restrict__ ctxb) {
    __shared__ unsigned short Ks[256 * 72];   // K rows x d, stride 72 (2-way free)
    __shared__ unsigned short Vt[64 * 264];   // V^T: d rows x s, stride 264
    __shared__ unsigned short Ps[4][16 * 72]; // per-wave P chunk (16 q x 64 k)

    const int blk = blockIdx.x;
    const int qc = blk & 3;
    const int hh = (blk >> 2) % NH;
    const int b = blk / (4 * NH);
    const int t = threadIdx.x;
    const int l = t & 63, w = t >> 6;
    const int l15 = l & 15, g = l >> 4;

    // stage K
    {
        const int c0 = (t & 7) << 3;
        int r = t >> 3;
#pragma unroll
        for (int it = 0; it < 8; ++it, r += 32) {
            u16x8 kv = *(const u16x8*)&qkv[(size_t)(b * S + r) * QKVS + H + hh * 64 + c0];
            *(u16x8*)&Ks[r * 72 + c0] = kv;
        }
    }
    // stage V^T (linear from pre-transposed global)
    {
        const int s0 = (t & 31) << 3;
        int d = t >> 5;
#pragma unroll
        for (int it = 0; it < 8; ++it, d += 8) {
            u16x8 vv = *(const u16x8*)&vtg[(size_t)(blk >> 2) * (64 * 256) + d * 256 + s0];
            *(u16x8*)&Vt[d * 264 + s0] = vv;
        }
    }
    // Q frags straight to regs (row = l15 within wave's 16 q-rows)
    const int qrow = qc * 64 + w * 16 + l15;
    const unsigned short* qp = &qkv[(size_t)(b * S + qrow) * QKVS + hh * 64 + g * 8];
    bf16x8 aq0 = *(const bf16x8*)qp;
    bf16x8 aq1 = *(const bf16x8*)(qp + 32);
    __syncthreads();

    // QK^T: acc[n] covers cols n*16..+15; D layout: col=l15, row=g*4+j
    f32x4 acc[16];
#pragma unroll
    for (int n = 0; n < 16; ++n) acc[n] = (f32x4){0.f, 0.f, 0.f, 0.f};
#pragma unroll
    for (int n = 0; n < 16; ++n) {
        const unsigned short* kp = &Ks[(n * 16 + l15) * 72 + g * 8];
        bf16x8 b0 = *(const bf16x8*)kp;
        bf16x8 b1 = *(const bf16x8*)(kp + 32);
        acc[n] = __builtin_amdgcn_mfma_f32_16x16x32_bf16(aq0, b0, acc[n], 0, 0, 0);
        acc[n] = __builtin_amdgcn_mfma_f32_16x16x32_bf16(aq1, b1, acc[n], 0, 0, 0);
    }

    // in-register softmax per row (g*4+j); scale 1/8 folded into exp2
    float inv[4];
#pragma unroll
    for (int j = 0; j < 4; ++j) {
        float mx = acc[0][j];
#pragma unroll
        for (int n = 1; n < 16; ++n) mx = fmaxf(mx, acc[n][j]);
        mx = fmaxf(mx, __shfl_xor(mx, 1));
        mx = fmaxf(mx, __shfl_xor(mx, 2));
        mx = fmaxf(mx, __shfl_xor(mx, 4));
        mx = fmaxf(mx, __shfl_xor(mx, 8));
        float sum = 0.f;
#pragma unroll
        for (int n = 0; n < 16; ++n) {
            float e = exp2f((acc[n][j] - mx) * 0.18033688011112042f);
            acc[n][j] = e;
            sum += e;
        }
        sum += __shfl_xor(sum, 1);
        sum += __shfl_xor(sum, 2);
        sum += __shfl_xor(sum, 4);
        sum += __shfl_xor(sum, 8);
        inv[j] = 1.0f / sum;   // deferred normalization (applied in epilogue)
    }

    // PV in 4 k-chunks of 64 through per-wave private LDS (no barriers)
    f32x4 cacc[4];
#pragma unroll
    for (int nd = 0; nd < 4; ++nd) cacc[nd] = (f32x4){0.f, 0.f, 0.f, 0.f};
    unsigned short* ps = Ps[w];
#pragma unroll
    for (int c = 0; c < 4; ++c) {
#pragma unroll
        for (int nl = 0; nl < 4; ++nl) {
            int n = c * 4 + nl;
#pragma unroll
            for (int j = 0; j < 4; ++j)
                ps[(g * 4 + j) * 72 + nl * 16 + l15] = f2bf(acc[n][j]);
        }
        bf16x8 pa0 = *(const bf16x8*)&ps[l15 * 72 + g * 8];
        bf16x8 pa1 = *(const bf16x8*)&ps[l15 * 72 + 32 + g * 8];
#pragma unroll
        for (int nd = 0; nd < 4; ++nd) {
            const unsigned short* vp = &Vt[(nd * 16 + l15) * 264 + c * 64 + g * 8];
            bf16x8 v0 = *(const bf16x8*)vp;
            bf16x8 v1 = *(const bf16x8*)(vp + 32);
            cacc[nd] = __builtin_amdgcn_mfma_f32_16x16x32_bf16(pa0, v0, cacc[nd], 0, 0, 0);
            cacc[nd] = __builtin_amdgcn_mfma_f32_16x16x32_bf16(pa1, v1, cacc[nd], 0, 0, 0);
        }
    }

    // epilogue: ctx row = g*4+j (same lanes as inv[j])
#pragma unroll
    for (int nd = 0; nd < 4; ++nd)
#pragma unroll
        for (int j = 0; j < 4; ++j) {
            int qr = qc * 64 + w * 16 + g * 4 + j;
            ctxb[(size_t)(b * S + qr) * H + hh * 64 + nd * 16 + l15] = f2bf(cacc[nd][j] * inv[j]);
        }
}

// ---------------- Classifier ----------------
__global__ void clf_kernel(const float* __restrict__ h,
                           const float* __restrict__ W,
                           const float* __restrict__ bias,
                           float* __restrict__ logits) {
    int row = blockIdx.x;
    int t = threadIdx.x;
    float acc[T] = {};
    for (int kk = t; kk < H; kk += 256) {
        float x = h[(size_t)row * H + kk];
#pragma unroll
        for (int n = 0; n < T; ++n) acc[n] += x * W[kk * T + n];
    }
    __shared__ float red[256][T];
#pragma unroll
    for (int n = 0; n < T; ++n) red[t][n] = acc[n];
    __syncthreads();
    for (int off = 128; off > 0; off >>= 1) {
        if (t < off)
            for (int n = 0; n < T; ++n) red[t][n] += red[t + off][n];
        __syncthreads();
    }
    if (t < T) logits[(size_t)row * T + t] = red[0][t] + bias[t];
}

// ---------------- CRF ----------------
__global__ void crf_kernel(const float* __restrict__ logits,
                           const int* __restrict__ target,
                           const float* __restrict__ start,
                           const float* __restrict__ trans,
                           const float* __restrict__ endv,
                           float* __restrict__ llh) {
    int b = blockIdx.x;
    int t = threadIdx.x;
    __shared__ float alpha[T], alpha2[T];
    __shared__ float trs[T * T];
    __shared__ float numsh;
    for (int i = t; i < T * T; i += 64) trs[i] = trans[i];
    const float* lg = logits + (size_t)b * S * T;
    const int* tg = target + b * S;

    if (t == 0) {
        bool m0 = tg[0] > -1;
        int tag0 = m0 ? tg[0] : 0;
        float num = start[tag0] + lg[tag0];
        int cnt = m0 ? 1 : 0;
        int ptag = tag0;
        for (int s = 1; s < S; ++s) {
            bool m = tg[s] > -1;
            int tag = m ? tg[s] : 0;
            float e = lg[s * T + tag];
            float tr = trans[ptag * T + tag];
            if (m) { num += tr + e; cnt += 1; }
            ptag = tag;
        }
        int lastIdx = cnt - 1;
        if (lastIdx < 0) lastIdx = 0;
        int lastTag = (tg[lastIdx] > -1) ? tg[lastIdx] : 0;
        num += endv[lastTag];
        numsh = num;
    }
    if (t < T) alpha[t] = start[t] + lg[t];
    __syncthreads();

    for (int s = 1; s < S; ++s) {
        bool m = tg[s] > -1;
        if (t < T) {
            float mx = -1e30f;
#pragma unroll
            for (int i = 0; i < T; ++i) mx = fmaxf(mx, alpha[i] + trs[i * T + t]);
            float sum = 0.f;
#pragma unroll
            for (int i = 0; i < T; ++i) sum += expf(alpha[i] + trs[i * T + t] - mx);
            float nxt = logf(sum) + mx + lg[s * T + t];
            alpha2[t] = m ? nxt : alpha[t];
        }
        __syncthreads();
        if (t < T) alpha[t] = alpha2[t];
        __syncthreads();
    }
    if (t == 0) {
        float mx = -1e30f;
        for (int i = 0; i < T; ++i) mx = fmaxf(mx, alpha[i] + endv[i]);
        float sum = 0.f;
        for (int i = 0; i < T; ++i) sum += expf(alpha[i] + endv[i] - mx);
        float denom = logf(sum) + mx;
        llh[b] = numsh - denom;
    }
}

__global__ void final_kernel(const float* __restrict__ llh, float* __restrict__ out) {
    if (threadIdx.x == 0) {
        float s = 0.f;
        for (int b = 0; b < B; ++b) s += llh[b];
        out[0] = -s / B;
    }
}

// ---------------- Host launch ----------------
extern "C" void kernel_launch(void* const* d_in, const int* in_sizes, int n_in,
                              void* d_out, int out_size, void* d_ws, size_t ws_size,
                              hipStream_t stream) {
    const int*   x        = (const int*)d_in[0];
    const int*   target   = (const int*)d_in[1];
    const float* word_emb = (const float*)d_in[2];
    const float* pos_emb  = (const float*)d_in[3];
    const float* type_emb = (const float*)d_in[4];
    const float* emb_ln_g = (const float*)d_in[5];
    const float* emb_ln_b = (const float*)d_in[6];
    const float* Wq = (const float*)d_in[7];
    const float* bq = (const float*)d_in[8];
    const float* Wk = (const float*)d_in[9];
    const float* bk = (const float*)d_in[10];
    const float* Wv = (const float*)d_in[11];
    const float* bv = (const float*)d_in[12];
    const float* Wo = (const float*)d_in[13];
    const float* bo = (const float*)d_in[14];
    const float* ln1_g = (const float*)d_in[15];
    const float* ln1_b = (const float*)d_in[16];
    const float* W1 = (const float*)d_in[17];
    const float* b1 = (const float*)d_in[18];
    const float* W2 = (const float*)d_in[19];
    const float* b2 = (const float*)d_in[20];
    const float* ln2_g = (const float*)d_in[21];
    const float* ln2_b = (const float*)d_in[22];
    const float* clf_W = (const float*)d_in[23];
    const float* clf_b = (const float*)d_in[24];
    const float* crf_start = (const float*)d_in[25];
    const float* crf_trans = (const float*)d_in[26];
    const float* crf_end   = (const float*)d_in[27];

    char* ws = (char*)d_ws;
    size_t off = 0;
    auto alloc = [&](size_t bytes) { void* p = ws + off; off += (bytes + 255) & ~255ull; return p; };

    unsigned short* wqkvT = (unsigned short*)alloc((size_t)L * 3 * H * H * 2);
    unsigned short* woT   = (unsigned short*)alloc((size_t)L * H * H * 2);
    unsigned short* w1T   = (unsigned short*)alloc((size_t)L * H * DFF * 2);
    unsigned short* w2T   = (unsigned short*)alloc((size_t)L * H * DFF * 2);
    float*          bcat  = (float*)alloc((size_t)L * QKVS * 4);
    float*          h     = (float*)alloc((size_t)M * H * 4);
    unsigned short* hb    = (unsigned short*)alloc((size_t)M * H * 2);
    unsigned short* qkvb  = (unsigned short*)alloc((size_t)M * QKVS * 2);
    unsigned short* vtg   = (unsigned short*)alloc((size_t)B * NH * DH * S * 2);
    unsigned short* ctxb  = (unsigned short*)alloc((size_t)M * H * 2);
    float*          go    = (float*)alloc((size_t)M * H * 4);
    unsigned short* ffb   = (unsigned short*)alloc((size_t)M * DFF * 2);
    float*          logits = (float*)alloc((size_t)M * T * 4);
    float*          llh    = (float*)alloc((size_t)B * 4);

    dim3 tb(32, 8);
    convT_kernel<<<dim3(H / 32, H / 32, L), tb, 0, stream>>>(Wq, wqkvT,             H, H, (size_t)3 * H * H);
    convT_kernel<<<dim3(H / 32, H / 32, L), tb, 0, stream>>>(Wk, wqkvT + H * H,     H, H, (size_t)3 * H * H);
    convT_kernel<<<dim3(H / 32, H / 32, L), tb, 0, stream>>>(Wv, wqkvT + 2 * H * H, H, H, (size_t)3 * H * H);
    convT_kernel<<<dim3(H / 32, H / 32, L), tb, 0, stream>>>(Wo, woT, H, H, (size_t)H * H);
    convT_kernel<<<dim3(DFF / 32, H / 32, L), tb, 0, stream>>>(W1, w1T, H, DFF, (size_t)H * DFF);
    convT_kernel<<<dim3(H / 32, DFF / 32, L), tb, 0, stream>>>(W2, w2T, DFF, H, (size_t)H * DFF);
    biascat_kernel<<<(L * QKVS + 255) / 256, 256, 0, stream>>>(bq, bk, bv, bcat);

    embed_ln_kernel<<<M, 256, 0, stream>>>(x, word_emb, pos_emb, type_emb, emb_ln_g, emb_ln_b, h, hb);

    const dim3 gQKV(QKVS / 128, M / 128);  // 18 x 32
    const dim3 gH(H / 128, M / 128);       // 6 x 32
    const dim3 gFF(DFF / 128, M / 128);    // 24 x 32

    for (int l = 0; l < L; ++l) {
        gemm_bf16<0, 0, 1><<<gQKV, 256, 0, stream>>>(hb, wqkvT + (size_t)l * 3 * H * H, bcat + l * QKVS,
                                                     nullptr, qkvb, H, QKVS);
        vtrans_kernel<<<B * NH, 256, 0, stream>>>(qkvb, vtg);
        attn_mfma<<<B * NH * 4, 256, 0, stream>>>(qkvb, vtg, ctxb);
        gemm_bf16<0, 1, 0><<<gH, 256, 0, stream>>>(ctxb, woT + (size_t)l * H * H, bo + l * H, go, nullptr, H, H);
        residual_ln_kernel<<<M, 256, 0, stream>>>(h, go, ln1_g + l * H, ln1_b + l * H, hb);
        gemm_bf16<1, 0, 1><<<gFF, 256, 0, stream>>>(hb, w1T + (size_t)l * H * DFF, b1 + l * DFF, nullptr, ffb, H, DFF);
        gemm_bf16<0, 1, 0><<<gH, 256, 0, stream>>>(ffb, w2T + (size_t)l * H * DFF, b2 + l * H, go, nullptr, DFF, H);
        residual_ln_kernel<<<M, 256, 0, stream>>>(h, go, ln2_g + l * H, ln2_b + l * H, hb);
    }

    clf_kernel<<<M, 256, 0, stream>>>(h, clf_W, clf_b, logits);
    crf_kernel<<<B, 64, 0, stream>>>(logits, target, crf_start, crf_trans, crf_end, llh);
    final_kernel<<<1, 64, 0, stream>>>(llh, (float*)d_out);
}

// Round 4
// 2297.555 us; speedup vs baseline: 6.9785x; 1.1069x over previous
//
#include <hip/hip_runtime.h>
#include <math.h>

#define B 16
#define S 256
#define H 768
#define NH 12
#define DH 64
#define DFF 3072
#define L 12
#define T 9
#define M (B*S)
#define LN_EPS 1e-12f
#define QKVS (3*H)

typedef __attribute__((ext_vector_type(8))) __bf16 bf16x8;
typedef __attribute__((ext_vector_type(8))) unsigned short u16x8;
typedef __attribute__((ext_vector_type(4))) unsigned short u16x4;
typedef __attribute__((ext_vector_type(4))) float f32x4;

__device__ __forceinline__ unsigned short f2bf(float f) {
    unsigned int u = __float_as_uint(f);
    unsigned int r = u + 0x7fffu + ((u >> 16) & 1u);
    return (unsigned short)(r >> 16);
}
__device__ __forceinline__ float bf2f(unsigned short h) {
    return __uint_as_float((unsigned int)h << 16);
}

// ---------------- Weight convert + transpose: W (K x N) f32 -> WT (N x K) bf16 ----------------
__global__ void convT_kernel(const float* __restrict__ W, unsigned short* __restrict__ WT,
                             int K, int N, size_t dstLayerStride) {
    __shared__ float tile[32][33];
    const int layer = blockIdx.z;
    const float* Wp = W + (size_t)layer * K * N;
    unsigned short* Tp = WT + (size_t)layer * dstLayerStride;
    const int n0 = blockIdx.x * 32, k0 = blockIdx.y * 32;
    const int tx = threadIdx.x, ty = threadIdx.y;  // 32 x 8
#pragma unroll
    for (int i = 0; i < 32; i += 8)
        tile[ty + i][tx] = Wp[(size_t)(k0 + ty + i) * N + n0 + tx];
    __syncthreads();
    {
        const int u = ty * 32 + tx;          // 0..255
        const int r = u >> 3, kq = (u & 7) << 2;
        u16x4 o;
#pragma unroll
        for (int j = 0; j < 4; ++j) o[j] = f2bf(tile[kq + j][r]);
        *(u16x4*)&Tp[(size_t)(n0 + r) * K + k0 + kq] = o;
    }
}

// ---------------- Concat QKV biases per layer: [L][2304] ----------------
__global__ void biascat_kernel(const float* __restrict__ bq, const float* __restrict__ bk,
                               const float* __restrict__ bv, float* __restrict__ out) {
    int idx = blockIdx.x * 256 + threadIdx.x;
    if (idx >= L * QKVS) return;
    int l = idx / QKVS, c = idx % QKVS;
    float v = (c < H) ? bq[l * H + c] : (c < 2 * H) ? bk[l * H + c - H] : bv[l * H + c - 2 * H];
    out[idx] = v;
}

// ---------------- Embedding + LayerNorm (192 threads, float4) ----------------
__global__ void embed_ln_kernel(const int* __restrict__ x,
                                const float* __restrict__ word_emb,
                                const float* __restrict__ pos_emb,
                                const float* __restrict__ type_emb,
                                const float* __restrict__ g,
                                const float* __restrict__ bta,
                                float* __restrict__ h,
                                unsigned short* __restrict__ hb) {
    const int row = blockIdx.x;
    const int s = row % S;
    const int tok = x[row];
    const int t = threadIdx.x;     // 192
    const int c = t << 2;
    const float4 wv = *(const float4*)&word_emb[(size_t)tok * H + c];
    const float4 pv = *(const float4*)&pos_emb[s * H + c];
    const float4 tv = *(const float4*)&type_emb[c];
    float v[4] = {wv.x + pv.x + tv.x, wv.y + pv.y + tv.y, wv.z + pv.z + tv.z, wv.w + pv.w + tv.w};
    float s1 = v[0] + v[1] + v[2] + v[3];
    float s2 = v[0]*v[0] + v[1]*v[1] + v[2]*v[2] + v[3]*v[3];
#pragma unroll
    for (int o = 32; o; o >>= 1) { s1 += __shfl_xor(s1, o); s2 += __shfl_xor(s2, o); }
    __shared__ float ws[3][2];
    const int w = t >> 6, l = t & 63;
    if (l == 0) { ws[w][0] = s1; ws[w][1] = s2; }
    __syncthreads();
    const float S1 = ws[0][0] + ws[1][0] + ws[2][0];
    const float S2 = ws[0][1] + ws[1][1] + ws[2][1];
    const float mean = S1 * (1.0f / H);
    const float var = fmaxf(S2 * (1.0f / H) - mean * mean, 0.f);
    const float inv = rsqrtf(var + LN_EPS);
    const float4 gv = *(const float4*)&g[c];
    const float4 bv = *(const float4*)&bta[c];
    float4 outv;
    outv.x = (v[0] - mean) * inv * gv.x + bv.x;
    outv.y = (v[1] - mean) * inv * gv.y + bv.y;
    outv.z = (v[2] - mean) * inv * gv.z + bv.z;
    outv.w = (v[3] - mean) * inv * gv.w + bv.w;
    *(float4*)&h[(size_t)row * H + c] = outv;
    u16x4 ob = {f2bf(outv.x), f2bf(outv.y), f2bf(outv.z), f2bf(outv.w)};
    *(u16x4*)&hb[(size_t)row * H + c] = ob;
}

// ---------------- Residual + LayerNorm (192 threads, float4, in-place) ----------------
__global__ void residual_ln_kernel(float* __restrict__ h,
                                   const float* __restrict__ delta,
                                   const float* __restrict__ g,
                                   const float* __restrict__ bta,
                                   unsigned short* __restrict__ hb) {
    const int row = blockIdx.x;
    const int t = threadIdx.x;     // 192
    const int c = t << 2;
    const float4 hv = *(const float4*)&h[(size_t)row * H + c];
    const float4 dv = *(const float4*)&delta[(size_t)row * H + c];
    float v[4] = {hv.x + dv.x, hv.y + dv.y, hv.z + dv.z, hv.w + dv.w};
    float s1 = v[0] + v[1] + v[2] + v[3];
    float s2 = v[0]*v[0] + v[1]*v[1] + v[2]*v[2] + v[3]*v[3];
#pragma unroll
    for (int o = 32; o; o >>= 1) { s1 += __shfl_xor(s1, o); s2 += __shfl_xor(s2, o); }
    __shared__ float ws[3][2];
    const int w = t >> 6, l = t & 63;
    if (l == 0) { ws[w][0] = s1; ws[w][1] = s2; }
    __syncthreads();
    const float S1 = ws[0][0] + ws[1][0] + ws[2][0];
    const float S2 = ws[0][1] + ws[1][1] + ws[2][1];
    const float mean = S1 * (1.0f / H);
    const float var = fmaxf(S2 * (1.0f / H) - mean * mean, 0.f);
    const float inv = rsqrtf(var + LN_EPS);
    const float4 gv = *(const float4*)&g[c];
    const float4 bv = *(const float4*)&bta[c];
    float4 outv;
    outv.x = (v[0] - mean) * inv * gv.x + bv.x;
    outv.y = (v[1] - mean) * inv * gv.y + bv.y;
    outv.z = (v[2] - mean) * inv * gv.z + bv.z;
    outv.w = (v[3] - mean) * inv * gv.w + bv.w;
    *(float4*)&h[(size_t)row * H + c] = outv;
    u16x4 ob = {f2bf(outv.x), f2bf(outv.y), f2bf(outv.z), f2bf(outv.w)};
    *(u16x4*)&hb[(size_t)row * H + c] = ob;
}

// ---------------- bf16 MFMA GEMM: C = A(MxK) @ WT^T + bias ----------------
// Tile: (MR*32) x 128, 4 waves (2x2), wave = (MR*16) x 64 of 16x16x32 frags.
#define LSTR 56

template<int ACT, int WF, int WB, int MR>
__global__ __launch_bounds__(256, (MR == 2 ? 3 : 2))
void gemm_bf16(const unsigned short* __restrict__ A,
               const unsigned short* __restrict__ WT,
               const float* __restrict__ bias,
               float* __restrict__ Cf,
               unsigned short* __restrict__ Cb,
               int K, int N) {
    __shared__ unsigned short lA[MR * 32 * LSTR];
    __shared__ unsigned short lB[128 * LSTR];
    const int tid = threadIdx.x;
    const int m0 = blockIdx.y * (MR * 32), n0 = blockIdx.x << 7;
    const int l = tid & 63, w = tid >> 6;
    const int wr = w >> 1, wc = w & 1;
    const int lr = l & 15, kg = l >> 4;

    const int srow = tid >> 2, scol = (tid & 3) << 3;
    const unsigned short* gA0 = A + (size_t)(m0 + srow) * K + scol;
    const unsigned short* gA1 = (MR == 4) ? gA0 + (size_t)64 * K : gA0;
    const unsigned short* gB0 = WT + (size_t)(n0 + srow) * K + scol;
    const unsigned short* gB1 = gB0 + (size_t)64 * K;
    u16x8* sA0 = (u16x8*)&lA[srow * LSTR + scol];
    u16x8* sA1 = (u16x8*)&lA[(srow + 64) * LSTR + scol];
    u16x8* sB0 = (u16x8*)&lB[srow * LSTR + scol];
    u16x8* sB1 = (u16x8*)&lB[(srow + 64) * LSTR + scol];

    f32x4 acc[MR][4];
#pragma unroll
    for (int i = 0; i < MR; ++i)
#pragma unroll
        for (int j = 0; j < 4; ++j) acc[i][j] = (f32x4){0.f, 0.f, 0.f, 0.f};

    u16x8 ra0 = *(const u16x8*)gA0;
    u16x8 ra1 = {};
    if constexpr (MR == 4) ra1 = *(const u16x8*)gA1;
    u16x8 rb0 = *(const u16x8*)gB0;
    u16x8 rb1 = *(const u16x8*)gB1;

    for (int kt = 0; kt < K; kt += 32) {
        *sA0 = ra0;
        if constexpr (MR == 4) *sA1 = ra1;
        *sB0 = rb0; *sB1 = rb1;
        __syncthreads();
        if (kt + 32 < K) {
            ra0 = *(const u16x8*)(gA0 + kt + 32);
            if constexpr (MR == 4) ra1 = *(const u16x8*)(gA1 + kt + 32);
            rb0 = *(const u16x8*)(gB0 + kt + 32);
            rb1 = *(const u16x8*)(gB1 + kt + 32);
        }
        bf16x8 af[MR], bfr[4];
#pragma unroll
        for (int m = 0; m < MR; ++m)
            af[m] = *(const bf16x8*)&lA[((wr * (MR * 16)) + (m << 4) + lr) * LSTR + (kg << 3)];
#pragma unroll
        for (int n = 0; n < 4; ++n)
            bfr[n] = *(const bf16x8*)&lB[((wc << 6) + (n << 4) + lr) * LSTR + (kg << 3)];
#pragma unroll
        for (int m = 0; m < MR; ++m)
#pragma unroll
            for (int n = 0; n < 4; ++n)
                acc[m][n] = __builtin_amdgcn_mfma_f32_16x16x32_bf16(af[m], bfr[n], acc[m][n], 0, 0, 0);
        __syncthreads();
    }

    const int rbase = m0 + wr * (MR * 16) + ((l >> 4) << 2);
    const int cbase = n0 + (wc << 6) + (l & 15);
#pragma unroll
    for (int m = 0; m < MR; ++m) {
#pragma unroll
        for (int n = 0; n < 4; ++n) {
            const int col = cbase + (n << 4);
            const float bv = bias[col];
#pragma unroll
            for (int j = 0; j < 4; ++j) {
                const int row = rbase + (m << 4) + j;
                float v = acc[m][n][j] + bv;
                if (ACT == 1) v = 0.5f * v * (1.0f + erff(v * 0.70710678118654752440f));
                if (WF) Cf[(size_t)row * N + col] = v;
                if (WB) Cb[(size_t)row * N + col] = f2bf(v);
            }
        }
    }
}

// ---------------- V transpose: qkv[.., 2H + h*64 + d] -> vtg[b*NH+h][d][s] ----------------
__global__ void vtrans_kernel(const unsigned short* __restrict__ qkv,
                              unsigned short* __restrict__ vtg) {
    __shared__ unsigned short tile[64 * 264];
    const int bh = blockIdx.x;
    const int b = bh / NH, hh = bh % NH;
    const int t = threadIdx.x;
    {
        const int d0 = (t & 7) << 3;
        int s = t >> 3;
#pragma unroll
        for (int it = 0; it < 8; ++it, s += 32) {
            u16x8 v = *(const u16x8*)&qkv[(size_t)(b * S + s) * QKVS + 2 * H + hh * 64 + d0];
#pragma unroll
            for (int j = 0; j < 8; ++j) {
                int d = d0 + j;
                tile[d * 264 + (s ^ (((d >> 3) & 7) << 3))] = v[j];
            }
        }
    }
    __syncthreads();
    {
        const int s0 = (t & 31) << 3;
        int d = t >> 5;
#pragma unroll
        for (int it = 0; it < 8; ++it, d += 8) {
            int sp = s0 ^ (((d >> 3) & 7) << 3);
            u16x8 v = *(const u16x8*)&tile[d * 264 + sp];
            *(u16x8*)&vtg[(size_t)bh * (64 * 256) + d * 256 + s0] = v;
        }
    }
}

// ---------------- MFMA attention ----------------
__global__ __launch_bounds__(256, 2)
void attn_mfma(const unsigned short* __restrict__ qkv,
               const unsigned short* __restrict__ vtg,
               unsigned short* __restrict__ ctxb) {
    __shared__ unsigned short Ks[256 * 72];
    __shared__ unsigned short Vt[64 * 264];
    __shared__ unsigned short Ps[4][16 * 72];

    const int blk = blockIdx.x;
    const int qc = blk & 3;
    const int hh = (blk >> 2) % NH;
    const int b = blk / (4 * NH);
    const int t = threadIdx.x;
    const int l = t & 63, w = t >> 6;
    const int l15 = l & 15, g = l >> 4;

    {
        const int c0 = (t & 7) << 3;
        int r = t >> 3;
#pragma unroll
        for (int it = 0; it < 8; ++it, r += 32) {
            u16x8 kv = *(const u16x8*)&qkv[(size_t)(b * S + r) * QKVS + H + hh * 64 + c0];
            *(u16x8*)&Ks[r * 72 + c0] = kv;
        }
    }
    {
        const int s0 = (t & 31) << 3;
        int d = t >> 5;
#pragma unroll
        for (int it = 0; it < 8; ++it, d += 8) {
            u16x8 vv = *(const u16x8*)&vtg[(size_t)(blk >> 2) * (64 * 256) + d * 256 + s0];
            *(u16x8*)&Vt[d * 264 + s0] = vv;
        }
    }
    const int qrow = qc * 64 + w * 16 + l15;
    const unsigned short* qp = &qkv[(size_t)(b * S + qrow) * QKVS + hh * 64 + g * 8];
    bf16x8 aq0 = *(const bf16x8*)qp;
    bf16x8 aq1 = *(const bf16x8*)(qp + 32);
    __syncthreads();

    f32x4 acc[16];
#pragma unroll
    for (int n = 0; n < 16; ++n) acc[n] = (f32x4){0.f, 0.f, 0.f, 0.f};
#pragma unroll
    for (int n = 0; n < 16; ++n) {
        const unsigned short* kp = &Ks[(n * 16 + l15) * 72 + g * 8];
        bf16x8 b0 = *(const bf16x8*)kp;
        bf16x8 b1 = *(const bf16x8*)(kp + 32);
        acc[n] = __builtin_amdgcn_mfma_f32_16x16x32_bf16(aq0, b0, acc[n], 0, 0, 0);
        acc[n] = __builtin_amdgcn_mfma_f32_16x16x32_bf16(aq1, b1, acc[n], 0, 0, 0);
    }

    float inv[4];
#pragma unroll
    for (int j = 0; j < 4; ++j) {
        float mx = acc[0][j];
#pragma unroll
        for (int n = 1; n < 16; ++n) mx = fmaxf(mx, acc[n][j]);
        mx = fmaxf(mx, __shfl_xor(mx, 1));
        mx = fmaxf(mx, __shfl_xor(mx, 2));
        mx = fmaxf(mx, __shfl_xor(mx, 4));
        mx = fmaxf(mx, __shfl_xor(mx, 8));
        float sum = 0.f;
#pragma unroll
        for (int n = 0; n < 16; ++n) {
            float e = exp2f((acc[n][j] - mx) * 0.18033688011112042f);
            acc[n][j] = e;
            sum += e;
        }
        sum += __shfl_xor(sum, 1);
        sum += __shfl_xor(sum, 2);
        sum += __shfl_xor(sum, 4);
        sum += __shfl_xor(sum, 8);
        inv[j] = 1.0f / sum;
    }

    f32x4 cacc[4];
#pragma unroll
    for (int nd = 0; nd < 4; ++nd) cacc[nd] = (f32x4){0.f, 0.f, 0.f, 0.f};
    unsigned short* ps = Ps[w];
#pragma unroll
    for (int c = 0; c < 4; ++c) {
#pragma unroll
        for (int nl = 0; nl < 4; ++nl) {
            int n = c * 4 + nl;
#pragma unroll
            for (int j = 0; j < 4; ++j)
                ps[(g * 4 + j) * 72 + nl * 16 + l15] = f2bf(acc[n][j]);
        }
        bf16x8 pa0 = *(const bf16x8*)&ps[l15 * 72 + g * 8];
        bf16x8 pa1 = *(const bf16x8*)&ps[l15 * 72 + 32 + g * 8];
#pragma unroll
        for (int nd = 0; nd < 4; ++nd) {
            const unsigned short* vp = &Vt[(nd * 16 + l15) * 264 + c * 64 + g * 8];
            bf16x8 v0 = *(const bf16x8*)vp;
            bf16x8 v1 = *(const bf16x8*)(vp + 32);
            cacc[nd] = __builtin_amdgcn_mfma_f32_16x16x32_bf16(pa0, v0, cacc[nd], 0, 0, 0);
            cacc[nd] = __builtin_amdgcn_mfma_f32_16x16x32_bf16(pa1, v1, cacc[nd], 0, 0, 0);
        }
    }

#pragma unroll
    for (int nd = 0; nd < 4; ++nd)
#pragma unroll
        for (int j = 0; j < 4; ++j) {
            int qr = qc * 64 + w * 16 + g * 4 + j;
            ctxb[(size_t)(b * S + qr) * H + hh * 64 + nd * 16 + l15] = f2bf(cacc[nd][j] * inv[j]);
        }
}

// ---------------- Classifier: one wave per row ----------------
__global__ void clf_kernel(const float* __restrict__ h,
                           const float* __restrict__ W,
                           const float* __restrict__ bias,
                           float* __restrict__ logits) {
    const int row = blockIdx.x * 4 + (threadIdx.x >> 6);
    const int l = threadIdx.x & 63;
    const float* hp = h + (size_t)row * H;
    float acc[T] = {};
#pragma unroll
    for (int i = 0; i < 12; ++i) {
        const int k = l + (i << 6);
        const float x = hp[k];
        const float* wp = &W[k * T];
#pragma unroll
        for (int n = 0; n < T; ++n) acc[n] += x * wp[n];
    }
#pragma unroll
    for (int o = 32; o; o >>= 1)
#pragma unroll
        for (int n = 0; n < T; ++n) acc[n] += __shfl_xor(acc[n], o);
    if (l < T) logits[(size_t)row * T + l] = acc[l] + bias[l];
}

// ---------------- CRF: fully parallel numerator + register scan, one block ----------------
__global__ void crf_kernel(const float* __restrict__ logits,
                           const int* __restrict__ target,
                           const float* __restrict__ start,
                           const float* __restrict__ trans,
                           const float* __restrict__ endv,
                           float* __restrict__ out) {
    const int t = threadIdx.x;       // 256
    const int b = t >> 4, li = t & 15;
    const float* lg = logits + (size_t)b * S * T;
    const int* tg = target + b * S;

    // ---- numerator: parallel over s, shfl-reduce within 16-lane group ----
    float pnum = 0.f; int pcnt = 0;
#pragma unroll
    for (int c = 0; c < 16; ++c) {
        const int s = 1 + li + (c << 4);
        if (s < S) {
            const int tcur = tg[s], tprev = tg[s - 1];
            const bool m = tcur > -1;
            const int tag = m ? tcur : 0;
            const int ptag = (tprev > -1) ? tprev : 0;
            if (m) { pnum += trans[ptag * T + tag] + lg[s * T + tag]; pcnt += 1; }
        }
    }
#pragma unroll
    for (int o = 8; o; o >>= 1) { pnum += __shfl_xor(pnum, o); pcnt += __shfl_xor(pcnt, o); }
    const bool m0 = tg[0] > -1;
    const int tag0 = m0 ? tg[0] : 0;
    const int cnt = pcnt + (m0 ? 1 : 0);
    int lastIdx = cnt - 1; if (lastIdx < 0) lastIdx = 0;
    const int lt = tg[lastIdx];
    const int lastTag = (lt > -1) ? lt : 0;
    const float num = start[tag0] + lg[tag0] + pnum + endv[lastTag];

    // ---- forward scan: alpha in registers, shfl gather within group ----
    float tr[T];
    if (li < T) {
#pragma unroll
        for (int j = 0; j < T; ++j) tr[j] = trans[j * T + li];
    } else {
#pragma unroll
        for (int j = 0; j < T; ++j) tr[j] = 0.f;
    }
    float alpha = (li < T) ? (start[li] + lg[li]) : -1e30f;
    const int gb = (t & 48);   // within-wave 16-lane group base

    float em_n1 = (li < T) ? lg[T + li] : 0.f;
    float em_n2 = (li < T) ? lg[2 * T + li] : 0.f;
    int tg_n1 = tg[1], tg_n2 = (S > 2) ? tg[2] : -1;
    for (int s = 1; s < S; ++s) {
        const float em = em_n1;
        const int tgc = tg_n1;
        em_n1 = em_n2; tg_n1 = tg_n2;
        if (s + 2 < S) {
            em_n2 = (li < T) ? lg[(s + 2) * T + li] : 0.f;
            tg_n2 = tg[s + 2];
        }
        float v0 = __shfl(alpha, gb + 0) + tr[0];
        float v1 = __shfl(alpha, gb + 1) + tr[1];
        float v2 = __shfl(alpha, gb + 2) + tr[2];
        float v3 = __shfl(alpha, gb + 3) + tr[3];
        float v4 = __shfl(alpha, gb + 4) + tr[4];
        float v5 = __shfl(alpha, gb + 5) + tr[5];
        float v6 = __shfl(alpha, gb + 6) + tr[6];
        float v7 = __shfl(alpha, gb + 7) + tr[7];
        float v8 = __shfl(alpha, gb + 8) + tr[8];
        float mx = fmaxf(v0, v1);
        mx = fmaxf(mx, fmaxf(v2, v3));
        mx = fmaxf(mx, fmaxf(v4, v5));
        mx = fmaxf(mx, fmaxf(v6, v7));
        mx = fmaxf(mx, v8);
        const float k = 1.44269504088896340736f;
        float sum = exp2f((v0 - mx) * k) + exp2f((v1 - mx) * k) + exp2f((v2 - mx) * k)
                  + exp2f((v3 - mx) * k) + exp2f((v4 - mx) * k) + exp2f((v5 - mx) * k)
                  + exp2f((v6 - mx) * k) + exp2f((v7 - mx) * k) + exp2f((v8 - mx) * k);
        const float nxt = mx + 0.69314718055994530942f * log2f(sum) + em;
        if (tgc > -1) alpha = nxt;
    }

    // ---- denominator + final mean ----
    float val = (li < T) ? (alpha + endv[li]) : -1e30f;
    float mx = val;
#pragma unroll
    for (int o = 8; o; o >>= 1) mx = fmaxf(mx, __shfl_xor(mx, o));
    float sm = (li < T) ? exp2f((val - mx) * 1.44269504088896340736f) : 0.f;
#pragma unroll
    for (int o = 8; o; o >>= 1) sm += __shfl_xor(sm, o);
    const float denom = mx + 0.69314718055994530942f * log2f(sm);

    __shared__ float lsh[16];
    if (li == 0) lsh[b] = num - denom;
    __syncthreads();
    if (t == 0) {
        float s = 0.f;
#pragma unroll
        for (int i = 0; i < 16; ++i) s += lsh[i];
        out[0] = -s * (1.0f / 16.0f);
    }
}

// ---------------- Host launch ----------------
extern "C" void kernel_launch(void* const* d_in, const int* in_sizes, int n_in,
                              void* d_out, int out_size, void* d_ws, size_t ws_size,
                              hipStream_t stream) {
    const int*   x        = (const int*)d_in[0];
    const int*   target   = (const int*)d_in[1];
    const float* word_emb = (const float*)d_in[2];
    const float* pos_emb  = (const float*)d_in[3];
    const float* type_emb = (const float*)d_in[4];
    const float* emb_ln_g = (const float*)d_in[5];
    const float* emb_ln_b = (const float*)d_in[6];
    const float* Wq = (const float*)d_in[7];
    const float* bq = (const float*)d_in[8];
    const float* Wk = (const float*)d_in[9];
    const float* bk = (const float*)d_in[10];
    const float* Wv = (const float*)d_in[11];
    const float* bv = (const float*)d_in[12];
    const float* Wo = (const float*)d_in[13];
    const float* bo = (const float*)d_in[14];
    const float* ln1_g = (const float*)d_in[15];
    const float* ln1_b = (const float*)d_in[16];
    const float* W1 = (const float*)d_in[17];
    const float* b1 = (const float*)d_in[18];
    const float* W2 = (const float*)d_in[19];
    const float* b2 = (const float*)d_in[20];
    const float* ln2_g = (const float*)d_in[21];
    const float* ln2_b = (const float*)d_in[22];
    const float* clf_W = (const float*)d_in[23];
    const float* clf_b = (const float*)d_in[24];
    const float* crf_start = (const float*)d_in[25];
    const float* crf_trans = (const float*)d_in[26];
    const float* crf_end   = (const float*)d_in[27];

    char* ws = (char*)d_ws;
    size_t off = 0;
    auto alloc = [&](size_t bytes) { void* p = ws + off; off += (bytes + 255) & ~255ull; return p; };

    unsigned short* wqkvT = (unsigned short*)alloc((size_t)L * 3 * H * H * 2);
    unsigned short* woT   = (unsigned short*)alloc((size_t)L * H * H * 2);
    unsigned short* w1T   = (unsigned short*)alloc((size_t)L * H * DFF * 2);
    unsigned short* w2T   = (unsigned short*)alloc((size_t)L * H * DFF * 2);
    float*          bcat  = (float*)alloc((size_t)L * QKVS * 4);
    float*          h     = (float*)alloc((size_t)M * H * 4);
    unsigned short* hb    = (unsigned short*)alloc((size_t)M * H * 2);
    unsigned short* qkvb  = (unsigned short*)alloc((size_t)M * QKVS * 2);
    unsigned short* vtg   = (unsigned short*)alloc((size_t)B * NH * DH * S * 2);
    unsigned short* ctxb  = (unsigned short*)alloc((size_t)M * H * 2);
    float*          go    = (float*)alloc((size_t)M * H * 4);
    unsigned short* ffb   = (unsigned short*)alloc((size_t)M * DFF * 2);
    float*          logits = (float*)alloc((size_t)M * T * 4);

    dim3 tb(32, 8);
    convT_kernel<<<dim3(H / 32, H / 32, L), tb, 0, stream>>>(Wq, wqkvT,             H, H, (size_t)3 * H * H);
    convT_kernel<<<dim3(H / 32, H / 32, L), tb, 0, stream>>>(Wk, wqkvT + H * H,     H, H, (size_t)3 * H * H);
    convT_kernel<<<dim3(H / 32, H / 32, L), tb, 0, stream>>>(Wv, wqkvT + 2 * H * H, H, H, (size_t)3 * H * H);
    convT_kernel<<<dim3(H / 32, H / 32, L), tb, 0, stream>>>(Wo, woT, H, H, (size_t)H * H);
    convT_kernel<<<dim3(DFF / 32, H / 32, L), tb, 0, stream>>>(W1, w1T, H, DFF, (size_t)H * DFF);
    convT_kernel<<<dim3(H / 32, DFF / 32, L), tb, 0, stream>>>(W2, w2T, DFF, H, (size_t)H * DFF);
    biascat_kernel<<<(L * QKVS + 255) / 256, 256, 0, stream>>>(bq, bk, bv, bcat);

    embed_ln_kernel<<<M, 192, 0, stream>>>(x, word_emb, pos_emb, type_emb, emb_ln_g, emb_ln_b, h, hb);

    const dim3 gQKV(QKVS / 128, M / 128);  // 18 x 32
    const dim3 gH64(H / 128, M / 64);      // 6 x 64  (MR=2)
    const dim3 gFF(DFF / 128, M / 128);    // 24 x 32

    for (int l = 0; l < L; ++l) {
        gemm_bf16<0, 0, 1, 4><<<gQKV, 256, 0, stream>>>(hb, wqkvT + (size_t)l * 3 * H * H, bcat + l * QKVS,
                                                        nullptr, qkvb, H, QKVS);
        vtrans_kernel<<<B * NH, 256, 0, stream>>>(qkvb, vtg);
        attn_mfma<<<B * NH * 4, 256, 0, stream>>>(qkvb, vtg, ctxb);
        gemm_bf16<0, 1, 0, 2><<<gH64, 256, 0, stream>>>(ctxb, woT + (size_t)l * H * H, bo + l * H, go, nullptr, H, H);
        residual_ln_kernel<<<M, 192, 0, stream>>>(h, go, ln1_g + l * H, ln1_b + l * H, hb);
        gemm_bf16<1, 0, 1, 4><<<gFF, 256, 0, stream>>>(hb, w1T + (size_t)l * H * DFF, b1 + l * DFF, nullptr, ffb, H, DFF);
        gemm_bf16<0, 1, 0, 2><<<gH64, 256, 0, stream>>>(ffb, w2T + (size_t)l * H * DFF, b2 + l * H, go, nullptr, DFF, H);
        residual_ln_kernel<<<M, 192, 0, stream>>>(h, go, ln2_g + l * H, ln2_b + l * H, hb);
    }

    clf_kernel<<<M / 4, 256, 0, stream>>>(h, clf_W, clf_b, logits);
    crf_kernel<<<1, 256, 0, stream>>>(logits, target, crf_start, crf_trans, crf_end, (float*)d_out);
}